// Round 1
// baseline (571.140 us; speedup 1.0000x reference)
//
#include <hip/hip_runtime.h>
#include <hip/hip_bf16.h>
#include <math.h>

// Problem constants (fixed by reference): B=2,T=2048 -> N=4096 tokens
#define N_TOK 4096
#define D_DIM 1024
#define H_DIM 4096
#define E_NUM 8
#define NSLOT (N_TOK * 2)  // total assignments = N*TOPK = 8192

typedef short bf16x8 __attribute__((ext_vector_type(8)));
typedef float f32x4 __attribute__((ext_vector_type(4)));

// ---------------- helpers ----------------

__device__ __forceinline__ unsigned short f2bf(float f) {
  unsigned int u = __float_as_uint(f);
  u += 0x7FFFu + ((u >> 16) & 1u);  // round-to-nearest-even
  return (unsigned short)(u >> 16);
}

// async global->LDS, 16B per lane. LDS dest is wave-uniform base + lane*16
// (m104: per-lane scatter impossible; hence the XOR *source* swizzle below).
__device__ __forceinline__ void gld_lds16(const void* g, void* l) {
  __builtin_amdgcn_global_load_lds(
      (__attribute__((address_space(1))) void*)(g),
      (__attribute__((address_space(3))) void*)(l), 16, 0, 0);
}

// ---------------- small kernels ----------------

__global__ void init_ctrl(int* p) { p[threadIdx.x] = 0; }

__global__ void cvt_f32_bf16(const float* __restrict__ src,
                             unsigned short* __restrict__ dst, int n4) {
  int i = blockIdx.x * blockDim.x + threadIdx.x;
  if (i >= n4) return;
  float4 v = ((const float4*)src)[i];
  ushort4 o;
  o.x = f2bf(v.x); o.y = f2bf(v.y); o.z = f2bf(v.z); o.w = f2bf(v.w);
  ((ushort4*)dst)[i] = o;
}

__global__ void zero_f32(float* __restrict__ p, int n4) {
  int i = blockIdx.x * blockDim.x + threadIdx.x;
  if (i < n4) ((float4*)p)[i] = make_float4(0.f, 0.f, 0.f, 0.f);
}

// ---------------- gating: atomic-free ----------------

__global__ void gating_kernel(const float* __restrict__ x,
                              const float* __restrict__ wg,
                              float* __restrict__ probs,   // [N_TOK][E]
                              int* __restrict__ eidx,
                              float* __restrict__ rw) {
  __shared__ float4 wg_lds[2048];  // 8*1024 floats = 32 KB
  const int t = threadIdx.x;
  const int lane = t & 63;
  const int wave = t >> 6;

#pragma unroll
  for (int j = 0; j < 8; ++j)
    wg_lds[t + 256 * j] = ((const float4*)wg)[t + 256 * j];
  __syncthreads();

#pragma unroll
  for (int j = 0; j < 4; ++j) {
    const int n = blockIdx.x * 16 + wave * 4 + j;
    const float4* xr = (const float4*)(x + (size_t)n * D_DIM);

    float acc[E_NUM];
#pragma unroll
    for (int e = 0; e < E_NUM; ++e) acc[e] = 0.f;

#pragma unroll
    for (int i = 0; i < 4; ++i) {
      float4 xv = xr[lane + 64 * i];
#pragma unroll
      for (int e = 0; e < E_NUM; ++e) {
        float4 wv = wg_lds[e * 256 + lane + 64 * i];
        acc[e] += xv.x * wv.x + xv.y * wv.y + xv.z * wv.z + xv.w * wv.w;
      }
    }
#pragma unroll
    for (int m = 1; m < 64; m <<= 1) {
#pragma unroll
      for (int e = 0; e < E_NUM; ++e) acc[e] += __shfl_xor(acc[e], m, 64);
    }

    float mx = acc[0];
#pragma unroll
    for (int e = 1; e < E_NUM; ++e) mx = fmaxf(mx, acc[e]);
    float p[E_NUM], s = 0.f;
#pragma unroll
    for (int e = 0; e < E_NUM; ++e) { p[e] = __expf(acc[e] - mx); s += p[e]; }
    float inv = 1.f / s;

    if (lane < E_NUM) probs[(size_t)n * E_NUM + lane] = p[lane] * inv;

    if (lane == 0) {
      int i1 = 0;
#pragma unroll
      for (int e = 1; e < E_NUM; ++e) if (p[e] > p[i1]) i1 = e;
      int i2 = (i1 == 0) ? 1 : 0;
#pragma unroll
      for (int e = 0; e < E_NUM; ++e)
        if (e != i1 && p[e] > p[i2]) i2 = e;
      float p1 = p[i1], p2 = p[i2];
      float wsum = 1.f / (p1 + p2);  // top-2 renormalize (softmax scale cancels)
      eidx[n] = i1 | (i2 << 8);
      rw[2 * n] = p1 * wsum;
      rw[2 * n + 1] = p2 * wsum;
    }
  }
}

// single block: sumP column-sums, expert histogram, offsets, balance loss
__global__ void reduce_route(const float* __restrict__ probs,
                             const int* __restrict__ eidx,
                             int* __restrict__ counts,
                             int* __restrict__ offsets,
                             float* __restrict__ loss) {
  const int t = threadIdx.x;
  float4 part = make_float4(0.f, 0.f, 0.f, 0.f);
  for (int j = 0; j < 32; ++j) {
    float4 v = ((const float4*)probs)[t + 256 * j];
    part.x += v.x; part.y += v.y; part.z += v.z; part.w += v.w;
  }
  int cnt[E_NUM];
#pragma unroll
  for (int e = 0; e < E_NUM; ++e) cnt[e] = 0;
  for (int j = 0; j < 16; ++j) {
    int pk = eidx[t + 256 * j];
    int e1 = pk & 255, e2 = pk >> 8;
#pragma unroll
    for (int e = 0; e < E_NUM; ++e) cnt[e] += (e1 == e) + (e2 == e);
  }

  __shared__ float redf[256 * E_NUM];
  __shared__ int redi[256 * E_NUM];
  const int eb = (t & 1) * 4;
#pragma unroll
  for (int e = 0; e < E_NUM; ++e) { redf[t * E_NUM + e] = 0.f; redi[t * E_NUM + e] = cnt[e]; }
  redf[t * E_NUM + eb + 0] = part.x;
  redf[t * E_NUM + eb + 1] = part.y;
  redf[t * E_NUM + eb + 2] = part.z;
  redf[t * E_NUM + eb + 3] = part.w;
  __syncthreads();
  for (int s = 128; s > 0; s >>= 1) {
    if (t < s) {
#pragma unroll
      for (int e = 0; e < E_NUM; ++e) {
        redf[t * E_NUM + e] += redf[(t + s) * E_NUM + e];
        redi[t * E_NUM + e] += redi[(t + s) * E_NUM + e];
      }
    }
    __syncthreads();
  }
  if (t == 0) {
    int o = 0;
    float L = 0.f;
    for (int e = 0; e < E_NUM; ++e) {
      int c = redi[e];
      counts[e] = c;
      offsets[e] = o;
      o += c;
      L += redf[e] * (float)c;
    }
    loss[0] = L * (float)E_NUM / ((float)N_TOK * (float)N_TOK);
  }
}

// two-phase scatter: LDS-local positions, one global atomic per expert/block
__global__ void scatter_kernel(const int* __restrict__ eidx, const float* __restrict__ rw,
                               const int* __restrict__ offsets, int* __restrict__ cursor,
                               int* __restrict__ tok_id, float* __restrict__ tok_w) {
  __shared__ int lcnt[E_NUM];
  __shared__ int lbase[E_NUM];
  const int t = threadIdx.x;
  const int n = blockIdx.x * 256 + t;
  if (t < E_NUM) lcnt[t] = 0;
  __syncthreads();
  int pk = eidx[n];
  int e1 = pk & 255, e2 = pk >> 8;
  int p1 = atomicAdd(&lcnt[e1], 1);
  int p2 = atomicAdd(&lcnt[e2], 1);
  __syncthreads();
  if (t < E_NUM) lbase[t] = atomicAdd(&cursor[t], lcnt[t]);
  __syncthreads();
  int d1 = offsets[e1] + lbase[e1] + p1;
  tok_id[d1] = n; tok_w[d1] = rw[2 * n];
  int d2 = offsets[e2] + lbase[e2] + p2;
  tok_id[d2] = n; tok_w[d2] = rw[2 * n + 1];
}

// ---------------- grouped GEMMs: 8-wave 256x128 tile, BK=64, LDS ring-3 ----
// T3+T4+T5 port of the counted-vmcnt pipeline (never drains in steady state):
//  - 8 waves (4M x 2N), each owns a 64x64 output tile -> 16 MFMA per phase,
//    2 phases (kk=0,32) per K-tile of 64. Per phase: 8 ds_read_b128 +
//    3 global_load_lds + raw s_barrier (NO implicit vmcnt(0) drain) + MFMA
//    cluster wrapped in s_setprio(1).
//  - LDS ring of 3 buffers (A 32KB + B 16KB each = 144 KB): computing kt from
//    buf[kt%3] while staging kt+2 into buf[(kt+2)%3]. That buffer's reads all
//    completed before the end-of-(kt-1) barrier (lgkm waits precede each
//    phase's MFMAs which precede the phase barrier) -> race-free.
//  - vmcnt proof: at end of kt, outstanding VMEM = (maybe) stage(kt+1) +
//    stage(kt+2)'s 6 loads (the 6 newest). s_waitcnt vmcnt(6) => stage(kt+1)
//    landed; the following s_barrier publishes all waves' portions. Only
//    kt==NK-2 drains to 0. No other VMEM ops exist inside the loop, so the
//    counts are exact.
//  - LDS swizzle: byte-identical to the measured-zero-conflict layout:
//    LDS(row, 16B-chunk c) holds global chunk c ^ (row & 7); readers use
//    chunk ((kk>>3)+q) ^ (lane&7). global_load_lds dest stays linear.

__launch_bounds__(512, 2)
__global__ void gemm_fc(const unsigned short* __restrict__ xb,    // [N_TOK][D]
                        const unsigned short* __restrict__ wfc,   // [E][H][D]
                        const int* __restrict__ tok_id,
                        const int* __restrict__ counts,
                        const int* __restrict__ offsets,
                        unsigned short* __restrict__ hbuf) {      // [NSLOT][H]
  const int e = blockIdx.z;
  const int cnt = counts[e];
  const int mtile = blockIdx.y;
  if (mtile * 256 >= cnt) return;
  const int ntile = blockIdx.x;
  const int off = offsets[e];

  __shared__ __align__(16) unsigned short lds[3 * 24576];  // 144 KB ring

  const int t = threadIdx.x;
  const int lane = t & 63;
  const int wave = t >> 6;
  const int wm = (wave >> 1) * 64;   // 4 waves along M
  const int wn = (wave & 1) * 64;    // 2 waves along N

  const int srow = t >> 3;                  // staged row within 64-row plane
  const int seg = (t & 7) ^ (srow & 7);     // XOR-swizzled source chunk

  const unsigned short* aptr[4];
  const unsigned short* bptr[2];
#pragma unroll
  for (int p = 0; p < 4; ++p) {
    int r = mtile * 256 + p * 64 + srow;
    r = (r < cnt) ? r : (cnt - 1);  // clamp: masked at store
    aptr[p] = xb + (size_t)tok_id[off + r] * D_DIM + seg * 8;
  }
#pragma unroll
  for (int p = 0; p < 2; ++p)
    bptr[p] = wfc + ((size_t)e * H_DIM + ntile * 128 + p * 64 + srow) * D_DIM + seg * 8;

  f32x4 acc[4][4];
#pragma unroll
  for (int i = 0; i < 4; ++i)
#pragma unroll
    for (int j = 0; j < 4; ++j) acc[i][j] = (f32x4){0.f, 0.f, 0.f, 0.f};

  const int fr = lane & 15;
  const int q = lane >> 4;
  const int csw = lane & 7;
  const int c0 = ((q ^ csw) << 3);          // kk=0  swizzled chunk offset
  const int c1 = (((q + 4) ^ csw) << 3);    // kk=32

  const int NK = D_DIM / 64;  // 16

  // prologue: stage kt=0 -> buf0, kt=1 -> buf1 (12 loads), wait first 6
#pragma unroll
  for (int p = 0; p < 4; ++p) gld_lds16(aptr[p], &lds[p * 4096 + t * 8]);
#pragma unroll
  for (int p = 0; p < 2; ++p) gld_lds16(bptr[p], &lds[16384 + p * 4096 + t * 8]);
#pragma unroll
  for (int p = 0; p < 4; ++p) gld_lds16(aptr[p] + 64, &lds[24576 + p * 4096 + t * 8]);
#pragma unroll
  for (int p = 0; p < 2; ++p) gld_lds16(bptr[p] + 64, &lds[24576 + 16384 + p * 4096 + t * 8]);
  asm volatile("s_waitcnt vmcnt(6)" ::: "memory");
  __builtin_amdgcn_s_barrier();

  int sb = 0;
  for (int kt = 0; kt < NK; ++kt) {
    int stS = sb + 2 * 24576; if (stS >= 3 * 24576) stS -= 3 * 24576;
    const unsigned short* Ab = &lds[sb + (wm + fr) * 64];
    const unsigned short* Bb = &lds[sb + 16384 + (wn + fr) * 64];
    const int kof = (kt + 2) * 64;
    bf16x8 a_[4], b_[4];

    // ---- phase 0 (kk = 0..31) ----
#pragma unroll
    for (int m = 0; m < 4; ++m) a_[m] = *(const bf16x8*)(Ab + m * 1024 + c0);
#pragma unroll
    for (int n = 0; n < 4; ++n) b_[n] = *(const bf16x8*)(Bb + n * 1024 + c0);
    if (kt + 2 < NK) {
      gld_lds16(aptr[0] + kof, &lds[stS + t * 8]);
      gld_lds16(aptr[1] + kof, &lds[stS + 4096 + t * 8]);
      gld_lds16(aptr[2] + kof, &lds[stS + 8192 + t * 8]);
    }
    __builtin_amdgcn_s_barrier();
    __builtin_amdgcn_s_setprio(1);
#pragma unroll
    for (int m = 0; m < 4; ++m)
#pragma unroll
      for (int n = 0; n < 4; ++n)
        acc[m][n] = __builtin_amdgcn_mfma_f32_16x16x32_bf16(a_[m], b_[n], acc[m][n], 0, 0, 0);
    __builtin_amdgcn_s_setprio(0);
    __builtin_amdgcn_s_barrier();

    // ---- phase 1 (kk = 32..63) ----
#pragma unroll
    for (int m = 0; m < 4; ++m) a_[m] = *(const bf16x8*)(Ab + m * 1024 + c1);
#pragma unroll
    for (int n = 0; n < 4; ++n) b_[n] = *(const bf16x8*)(Bb + n * 1024 + c1);
    if (kt + 2 < NK) {
      gld_lds16(aptr[3] + kof, &lds[stS + 12288 + t * 8]);
      gld_lds16(bptr[0] + kof, &lds[stS + 16384 + t * 8]);
      gld_lds16(bptr[1] + kof, &lds[stS + 20480 + t * 8]);
    }
    __builtin_amdgcn_s_barrier();
    __builtin_amdgcn_s_setprio(1);
#pragma unroll
    for (int m = 0; m < 4; ++m)
#pragma unroll
      for (int n = 0; n < 4; ++n)
        acc[m][n] = __builtin_amdgcn_mfma_f32_16x16x32_bf16(a_[m], b_[n], acc[m][n], 0, 0, 0);
    __builtin_amdgcn_s_setprio(0);
    if (kt < NK - 2)       asm volatile("s_waitcnt vmcnt(6)" ::: "memory");
    else if (kt == NK - 2) asm volatile("s_waitcnt vmcnt(0)" ::: "memory");
    __builtin_amdgcn_s_barrier();
    sb += 24576; if (sb >= 3 * 24576) sb = 0;
  }

  // epilogue: h = relu(t)^2, cast bf16, store
  const int lm = (lane >> 4) * 4;
  const int ln = lane & 15;
#pragma unroll
  for (int m = 0; m < 4; ++m) {
#pragma unroll
    for (int r = 0; r < 4; ++r) {
      int mm = mtile * 256 + wm + m * 16 + lm + r;
      if (mm < cnt) {
        size_t rowbase = (size_t)(off + mm) * H_DIM + ntile * 128 + wn;
#pragma unroll
        for (int n = 0; n < 4; ++n) {
          float v = acc[m][n][r];
          v = v > 0.f ? v * v : 0.f;
          hbuf[rowbase + n * 16 + ln] = f2bf(v);
        }
      }
    }
  }
}

// split-K=2: z = e*2 + khalf; both halves atomicAdd into zero-initialized out.
__launch_bounds__(512, 2)
__global__ void gemm_proj(const unsigned short* __restrict__ hbuf,   // [NSLOT][H]
                          const unsigned short* __restrict__ wproj,  // [E][D][H]
                          const int* __restrict__ tok_id,
                          const float* __restrict__ tok_w,
                          const int* __restrict__ counts,
                          const int* __restrict__ offsets,
                          float* __restrict__ out) {                 // [N_TOK][D]
  const int e = blockIdx.z >> 1;
  const int kbase = (blockIdx.z & 1) * (H_DIM / 2);
  const int cnt = counts[e];
  const int mtile = blockIdx.y;
  if (mtile * 256 >= cnt) return;
  const int ntile = blockIdx.x;  // 0..7 (D=1024, BN=128)
  const int off = offsets[e];

  __shared__ __align__(16) unsigned short lds[3 * 24576];  // 144 KB ring

  const int t = threadIdx.x;
  const int lane = t & 63;
  const int wave = t >> 6;
  const int wm = (wave >> 1) * 64;
  const int wn = (wave & 1) * 64;

  const int srow = t >> 3;
  const int seg = (t & 7) ^ (srow & 7);

  const unsigned short* aptr[4];
  const unsigned short* bptr[2];
#pragma unroll
  for (int p = 0; p < 4; ++p) {
    int r = mtile * 256 + p * 64 + srow;
    r = (r < cnt) ? r : (cnt - 1);
    aptr[p] = hbuf + (size_t)(off + r) * H_DIM + kbase + seg * 8;
  }
#pragma unroll
  for (int p = 0; p < 2; ++p)
    bptr[p] = wproj + ((size_t)e * D_DIM + ntile * 128 + p * 64 + srow) * H_DIM + kbase + seg * 8;

  f32x4 acc[4][4];
#pragma unroll
  for (int i = 0; i < 4; ++i)
#pragma unroll
    for (int j = 0; j < 4; ++j) acc[i][j] = (f32x4){0.f, 0.f, 0.f, 0.f};

  const int fr = lane & 15;
  const int q = lane >> 4;
  const int csw = lane & 7;
  const int c0 = ((q ^ csw) << 3);
  const int c1 = (((q + 4) ^ csw) << 3);

  const int NK = (H_DIM / 2) / 64;  // 32

#pragma unroll
  for (int p = 0; p < 4; ++p) gld_lds16(aptr[p], &lds[p * 4096 + t * 8]);
#pragma unroll
  for (int p = 0; p < 2; ++p) gld_lds16(bptr[p], &lds[16384 + p * 4096 + t * 8]);
#pragma unroll
  for (int p = 0; p < 4; ++p) gld_lds16(aptr[p] + 64, &lds[24576 + p * 4096 + t * 8]);
#pragma unroll
  for (int p = 0; p < 2; ++p) gld_lds16(bptr[p] + 64, &lds[24576 + 16384 + p * 4096 + t * 8]);
  asm volatile("s_waitcnt vmcnt(6)" ::: "memory");
  __builtin_amdgcn_s_barrier();

  int sb = 0;
  for (int kt = 0; kt < NK; ++kt) {
    int stS = sb + 2 * 24576; if (stS >= 3 * 24576) stS -= 3 * 24576;
    const unsigned short* Ab = &lds[sb + (wm + fr) * 64];
    const unsigned short* Bb = &lds[sb + 16384 + (wn + fr) * 64];
    const int kof = (kt + 2) * 64;
    bf16x8 a_[4], b_[4];

    // ---- phase 0 ----
#pragma unroll
    for (int m = 0; m < 4; ++m) a_[m] = *(const bf16x8*)(Ab + m * 1024 + c0);
#pragma unroll
    for (int n = 0; n < 4; ++n) b_[n] = *(const bf16x8*)(Bb + n * 1024 + c0);
    if (kt + 2 < NK) {
      gld_lds16(aptr[0] + kof, &lds[stS + t * 8]);
      gld_lds16(aptr[1] + kof, &lds[stS + 4096 + t * 8]);
      gld_lds16(aptr[2] + kof, &lds[stS + 8192 + t * 8]);
    }
    __builtin_amdgcn_s_barrier();
    __builtin_amdgcn_s_setprio(1);
#pragma unroll
    for (int m = 0; m < 4; ++m)
#pragma unroll
      for (int n = 0; n < 4; ++n)
        acc[m][n] = __builtin_amdgcn_mfma_f32_16x16x32_bf16(a_[m], b_[n], acc[m][n], 0, 0, 0);
    __builtin_amdgcn_s_setprio(0);
    __builtin_amdgcn_s_barrier();

    // ---- phase 1 ----
#pragma unroll
    for (int m = 0; m < 4; ++m) a_[m] = *(const bf16x8*)(Ab + m * 1024 + c1);
#pragma unroll
    for (int n = 0; n < 4; ++n) b_[n] = *(const bf16x8*)(Bb + n * 1024 + c1);
    if (kt + 2 < NK) {
      gld_lds16(aptr[3] + kof, &lds[stS + 12288 + t * 8]);
      gld_lds16(bptr[0] + kof, &lds[stS + 16384 + t * 8]);
      gld_lds16(bptr[1] + kof, &lds[stS + 20480 + t * 8]);
    }
    __builtin_amdgcn_s_barrier();
    __builtin_amdgcn_s_setprio(1);
#pragma unroll
    for (int m = 0; m < 4; ++m)
#pragma unroll
      for (int n = 0; n < 4; ++n)
        acc[m][n] = __builtin_amdgcn_mfma_f32_16x16x32_bf16(a_[m], b_[n], acc[m][n], 0, 0, 0);
    __builtin_amdgcn_s_setprio(0);
    if (kt < NK - 2)       asm volatile("s_waitcnt vmcnt(6)" ::: "memory");
    else if (kt == NK - 2) asm volatile("s_waitcnt vmcnt(0)" ::: "memory");
    __builtin_amdgcn_s_barrier();
    sb += 24576; if (sb >= 3 * 24576) sb = 0;
  }

  // epilogue: scale by routing weight, scatter-add into out
  const int lm = (lane >> 4) * 4;
  const int ln = lane & 15;
#pragma unroll
  for (int m = 0; m < 4; ++m) {
#pragma unroll
    for (int r = 0; r < 4; ++r) {
      int mm = mtile * 256 + wm + m * 16 + lm + r;
      if (mm < cnt) {
        int slot = off + mm;
        float w = tok_w[slot];
        float* orow = out + (size_t)tok_id[slot] * D_DIM + ntile * 128 + wn;
#pragma unroll
        for (int n = 0; n < 4; ++n)
          atomicAdd(&orow[n * 16 + ln], acc[m][n][r] * w);
      }
    }
  }
}

// ---------------- launch ----------------
// ws layout (bytes):
//   0        counts[8] | 64 cursor[8] | 128 offsets[8]
//   256      eidx[4096] | 16640 rw[8192] | 49408 tok_id[8192] | 82176 tok_w[8192]
//   114944   probs[4096*8]         (131072)
//   246016   x_bf16                (8388608)
//   8634624  wfc_bf16              (67108864)
//   75743488 wproj_bf16            (67108864)
//   142852352 hbuf                 (67108864)

extern "C" void kernel_launch(void* const* d_in, const int* in_sizes, int n_in,
                              void* d_out, int out_size, void* d_ws, size_t ws_size,
                              hipStream_t stream) {
  (void)in_sizes; (void)n_in; (void)out_size; (void)ws_size;
  const float* x = (const float*)d_in[0];
  const float* wg = (const float*)d_in[1];
  const float* wfc = (const float*)d_in[2];
  const float* wproj = (const float*)d_in[3];
  float* out = (float*)d_out;
  char* ws = (char*)d_ws;

  int* counts = (int*)(ws + 0);
  int* cursor = (int*)(ws + 64);
  int* offsets = (int*)(ws + 128);
  int* eidx = (int*)(ws + 256);
  float* rw = (float*)(ws + 16640);
  int* tok_id = (int*)(ws + 49408);
  float* tok_w = (float*)(ws + 82176);
  float* probs = (float*)(ws + 114944);
  unsigned short* xb = (unsigned short*)(ws + 246016);
  unsigned short* wfcb = (unsigned short*)(ws + 8634624);
  unsigned short* wpjb = (unsigned short*)(ws + 75743488);
  unsigned short* hbuf = (unsigned short*)(ws + 142852352);

  hipLaunchKernelGGL(init_ctrl, dim3(1), dim3(64), 0, stream, (int*)ws);
  hipLaunchKernelGGL(cvt_f32_bf16, dim3(32768), dim3(256), 0, stream, wfc, wfcb, 8388608);
  hipLaunchKernelGGL(cvt_f32_bf16, dim3(32768), dim3(256), 0, stream, wproj, wpjb, 8388608);
  hipLaunchKernelGGL(cvt_f32_bf16, dim3(4096), dim3(256), 0, stream, x, xb, 1048576);
  hipLaunchKernelGGL(zero_f32, dim3(4096), dim3(256), 0, stream, out, 1048576);
  hipLaunchKernelGGL(gating_kernel, dim3(256), dim3(256), 0, stream, x, wg, probs, eidx, rw);
  hipLaunchKernelGGL(reduce_route, dim3(1), dim3(256), 0, stream, probs, eidx, counts, offsets, out + 4194304);
  hipLaunchKernelGGL(scatter_kernel, dim3(16), dim3(256), 0, stream, eidx, rw, offsets, cursor, tok_id, tok_w);
  hipLaunchKernelGGL(gemm_fc, dim3(32, 16, 8), dim3(512), 0, stream, xb, wfcb, tok_id, counts, offsets, hbuf);
  hipLaunchKernelGGL(gemm_proj, dim3(8, 16, 16), dim3(512), 0, stream, hbuf, wpjb, tok_id, tok_w, counts, offsets, out);
}